// Round 1
// baseline (728.406 us; speedup 1.0000x reference)
//
#include <hip/hip_runtime.h>
#include <hip/hip_bf16.h>

#define N_ROWS 4096
#define IN_DIM 768
#define OUT_DIM 512

#define BM 128
#define BN 128
#define BK 64
#define LDT 72   // padded LDS row stride (elements): 144 B = 9*16 B, b128-aligned

using bf16x8 = __attribute__((ext_vector_type(8))) short;
using f32x4  = __attribute__((ext_vector_type(4))) float;

__device__ __constant__ int c_docmap[6] = {0, 1, 0, 2, 1, 2};

__device__ inline unsigned short f2bf(float f) {
    __hip_bfloat16 h = __float2bfloat16(f);
    return reinterpret_cast<unsigned short&>(h);
}

// ---------------- conversion kernels ----------------

__global__ void conv_docs(const float* __restrict__ d0, const float* __restrict__ d1,
                          const float* __restrict__ d2, unsigned short* __restrict__ Xb) {
    const size_t n1 = (size_t)N_ROWS * IN_DIM;           // 3,145,728
    size_t i = (size_t)blockIdx.x * blockDim.x + threadIdx.x;
    size_t idx = i * 4;
    if (idx >= 3 * n1) return;
    int d = (int)(idx / n1);
    size_t loc = idx - (size_t)d * n1;
    const float* src = (d == 0) ? d0 : ((d == 1) ? d1 : d2);
    float4 v = *(const float4*)(src + loc);
    ushort4 o;
    o.x = f2bf(v.x); o.y = f2bf(v.y); o.z = f2bf(v.z); o.w = f2bf(v.w);
    *(ushort4*)(Xb + idx) = o;
}

// in: [z][R][C] fp32  ->  out: [z][C][R] bf16
__global__ void transpose_conv(const float* __restrict__ in, unsigned short* __restrict__ out,
                               int R, int C) {
    __shared__ float tile[32][33];
    int z = blockIdx.z;
    const float* ip = in + (size_t)z * R * C;
    unsigned short* op = out + (size_t)z * R * C;
    int r0 = blockIdx.y * 32, c0 = blockIdx.x * 32;
    for (int j = threadIdx.y; j < 32; j += 8)
        tile[j][threadIdx.x] = ip[(size_t)(r0 + j) * C + c0 + threadIdx.x];
    __syncthreads();
    for (int j = threadIdx.y; j < 32; j += 8)
        op[(size_t)(c0 + j) * R + r0 + threadIdx.x] = f2bf(tile[threadIdx.x][j]);
}

// ---------------- shared GEMM helpers ----------------

__device__ inline void stage_tile(const unsigned short* __restrict__ G, int ld, int row0, int k0,
                                  unsigned short* lds, int tid) {
    // 128 rows x 64 k-cols, 16B chunks: 1024 chunks, 4 per thread
#pragma unroll
    for (int i = 0; i < 4; ++i) {
        int c = tid + i * 256;
        int r = c >> 3;
        int cc = (c & 7) * 8;
        uint4 v = *(const uint4*)(G + (size_t)(row0 + r) * ld + k0 + cc);
        *(uint4*)(lds + r * LDT + cc) = v;
    }
}

__device__ inline void mfma_step(const unsigned short* As, const unsigned short* Bs,
                                 int wrow, int wcol, int lane15, int quad, f32x4 acc[4][4]) {
#pragma unroll
    for (int kk = 0; kk < BK; kk += 32) {
        bf16x8 aF[4], bF[4];
#pragma unroll
        for (int t = 0; t < 4; ++t)
            aF[t] = *(const bf16x8*)(As + (wrow + t * 16 + lane15) * LDT + kk + quad * 8);
#pragma unroll
        for (int t = 0; t < 4; ++t)
            bF[t] = *(const bf16x8*)(Bs + (wcol + t * 16 + lane15) * LDT + kk + quad * 8);
#pragma unroll
        for (int mt = 0; mt < 4; ++mt)
#pragma unroll
            for (int nt = 0; nt < 4; ++nt)
                acc[mt][nt] = __builtin_amdgcn_mfma_f32_16x16x32_bf16(aF[mt], bF[nt], acc[mt][nt], 0, 0, 0);
    }
}

// C[m][n] = sum_k A[m][k] * B[n][k] + bias[n]   (B stored row-major [N][K], i.e. B^T form)
__global__ __launch_bounds__(256) void gemm_bt_bias(
    const unsigned short* __restrict__ Abase, size_t aStride, int useMap,
    const unsigned short* __restrict__ Bbase, const float* __restrict__ biasAll,
    float* __restrict__ Cbase, int M, int N, int K) {
    int z = blockIdx.z;
    const unsigned short* A = Abase + (useMap ? (size_t)c_docmap[z] : (size_t)z) * aStride;
    const unsigned short* B = Bbase + (size_t)z * (size_t)N * K;
    const float* bz = biasAll + (size_t)z * N;
    float* C = Cbase + (size_t)z * (size_t)M * N;

    int m0 = blockIdx.y * BM, n0 = blockIdx.x * BN;
    int tid = threadIdx.x;
    int wave = tid >> 6, lane = tid & 63;
    int lane15 = lane & 15, quad = lane >> 4;
    int wrow = (wave >> 1) * 64, wcol = (wave & 1) * 64;

    __shared__ unsigned short As[BM * LDT];
    __shared__ unsigned short Bs[BN * LDT];

    f32x4 acc[4][4];
#pragma unroll
    for (int mt = 0; mt < 4; ++mt)
#pragma unroll
        for (int nt = 0; nt < 4; ++nt)
            acc[mt][nt] = (f32x4){0.f, 0.f, 0.f, 0.f};

    for (int k0 = 0; k0 < K; k0 += BK) {
        stage_tile(A, K, m0, k0, As, tid);
        stage_tile(B, K, n0, k0, Bs, tid);
        __syncthreads();
        mfma_step(As, Bs, wrow, wcol, lane15, quad, acc);
        __syncthreads();
    }

#pragma unroll
    for (int mt = 0; mt < 4; ++mt)
#pragma unroll
        for (int nt = 0; nt < 4; ++nt) {
            int col = n0 + wcol + nt * 16 + lane15;
            float bv = bz[col];
#pragma unroll
            for (int r = 0; r < 4; ++r) {
                int row = m0 + wrow + mt * 16 + quad * 4 + r;
                C[(size_t)row * N + col] = acc[mt][nt][r] + bv;
            }
        }
}

// ---------------- BN stats / apply ----------------

// stats[(k*512+c)*2+{0,1}] = {sum, sumsq} over 4096 rows
__global__ void bn_stats(const float* __restrict__ H, float* __restrict__ stats) {
    int k = blockIdx.z;
    int c = blockIdx.x * 128 + threadIdx.x;
    int r0 = blockIdx.y * 512;
    const float* Hp = H + (size_t)k * N_ROWS * OUT_DIM;
    float s1 = 0.f, s2 = 0.f;
    for (int r = r0; r < r0 + 512; ++r) {
        float v = Hp[(size_t)r * OUT_DIM + c];
        s1 += v; s2 += v * v;
    }
    atomicAdd(&stats[((size_t)k * OUT_DIM + c) * 2 + 0], s1);
    atomicAdd(&stats[((size_t)k * OUT_DIM + c) * 2 + 1], s2);
}

__global__ void bn_apply(const float* __restrict__ H, const float* __restrict__ stats,
                         const float* __restrict__ gammas, const float* __restrict__ betas,
                         unsigned short* __restrict__ Hb) {
    size_t i = (size_t)blockIdx.x * blockDim.x + threadIdx.x;
    if (i >= (size_t)6 * N_ROWS * OUT_DIM) return;
    int c = (int)(i % OUT_DIM);
    int k = (int)(i / ((size_t)N_ROWS * OUT_DIM));
    size_t sc = (size_t)k * OUT_DIM + c;
    float s1 = stats[sc * 2 + 0], s2 = stats[sc * 2 + 1];
    float mu = s1 * (1.f / N_ROWS);
    float var = s2 * (1.f / N_ROWS) - mu * mu;
    float g = gammas[sc], b = betas[sc];
    float v = (H[i] - mu) * rsqrtf(var + 1e-5f) * g + b;
    v = fmaxf(v, 0.f);
    Hb[i] = f2bf(v);
}

// ---------------- row L2 norm -> bf16 ----------------

__global__ __launch_bounds__(256) void l2norm(const float* __restrict__ O,
                                              unsigned short* __restrict__ A) {
    int wave = threadIdx.x >> 6, lane = threadIdx.x & 63;
    int row = blockIdx.x * 4 + wave;   // 6*4096 rows
    const float* Op = O + (size_t)row * OUT_DIM;
    float4 v0 = *(const float4*)(Op + lane * 8);
    float4 v1 = *(const float4*)(Op + lane * 8 + 4);
    float ss = v0.x * v0.x + v0.y * v0.y + v0.z * v0.z + v0.w * v0.w
             + v1.x * v1.x + v1.y * v1.y + v1.z * v1.z + v1.w * v1.w;
#pragma unroll
    for (int m = 1; m < 64; m <<= 1) ss += __shfl_xor(ss, m);
    float nrm = sqrtf(ss);
    float sc = 1.f / fmaxf(nrm, 1e-12f);
    unsigned short* Ap = A + (size_t)row * OUT_DIM + lane * 8;
    ushort4 o0, o1;
    o0.x = f2bf(v0.x * sc); o0.y = f2bf(v0.y * sc); o0.z = f2bf(v0.z * sc); o0.w = f2bf(v0.w * sc);
    o1.x = f2bf(v1.x * sc); o1.y = f2bf(v1.y * sc); o1.z = f2bf(v1.z * sc); o1.w = f2bf(v1.w * sc);
    *(ushort4*)(Ap) = o0;
    *(ushort4*)(Ap + 4) = o1;
}

// ---------------- fused Gram + exp + row-sum ----------------

// Per pair p: C = Abuf + p*2*4096*512 is [8192][512] bf16 (rows L2-normalized).
// rowsum[p][i] += sum_j exp(2*c_i.c_j) over this block's columns;
// selfdot[p][i] = c_i.c_i ; crossdot[p][i] = c_i.c_{i^N}.
__global__ __launch_bounds__(256) void gram_kernel(const unsigned short* __restrict__ Abase,
                                                   float* __restrict__ rowsum,
                                                   float* __restrict__ selfdot,
                                                   float* __restrict__ crossdot) {
    const int K = OUT_DIM;          // 512
    int p = blockIdx.z;
    const unsigned short* Cm = Abase + (size_t)p * 2 * N_ROWS * OUT_DIM;
    int m0 = blockIdx.y * BM;
    int chunk = blockIdx.x;         // 0..3, 2048 cols each

    int tid = threadIdx.x;
    int wave = tid >> 6, lane = tid & 63;
    int lane15 = lane & 15, quad = lane >> 4;
    int wrow = (wave >> 1) * 64, wcol = (wave & 1) * 64;

    __shared__ unsigned short As[BM * LDT];
    __shared__ unsigned short Bs[BN * LDT];

    float rs[16];
#pragma unroll
    for (int j = 0; j < 16; ++j) rs[j] = 0.f;

    float* sdp = selfdot + (size_t)p * 2 * N_ROWS;
    float* cdp = crossdot + (size_t)p * 2 * N_ROWS;

    for (int t = 0; t < 16; ++t) {
        int n0 = chunk * 2048 + t * BN;
        f32x4 acc[4][4];
#pragma unroll
        for (int mt = 0; mt < 4; ++mt)
#pragma unroll
            for (int nt = 0; nt < 4; ++nt)
                acc[mt][nt] = (f32x4){0.f, 0.f, 0.f, 0.f};

        for (int k0 = 0; k0 < K; k0 += BK) {
            stage_tile(Cm, K, m0, k0, As, tid);
            stage_tile(Cm, K, n0, k0, Bs, tid);
            __syncthreads();
            mfma_step(As, Bs, wrow, wcol, lane15, quad, acc);
            __syncthreads();
        }

#pragma unroll
        for (int mt = 0; mt < 4; ++mt)
#pragma unroll
            for (int nt = 0; nt < 4; ++nt) {
                int gcol = n0 + wcol + nt * 16 + lane15;
#pragma unroll
                for (int r = 0; r < 4; ++r) {
                    int grow = m0 + wrow + mt * 16 + quad * 4 + r;
                    float s = acc[mt][nt][r];
                    rs[mt * 4 + r] += __expf(2.f * s);
                    if (gcol == grow) sdp[grow] = s;
                    if (gcol == grow + N_ROWS || gcol + N_ROWS == grow) cdp[grow] = s;
                }
            }
    }

    // reduce rs across the 16 lanes of each quad (lane15 dimension)
#pragma unroll
    for (int j = 0; j < 16; ++j) {
        float v = rs[j];
        v += __shfl_xor(v, 1);
        v += __shfl_xor(v, 2);
        v += __shfl_xor(v, 4);
        v += __shfl_xor(v, 8);
        rs[j] = v;
    }
    if (lane15 == 0) {
        float* rp = rowsum + (size_t)p * 2 * N_ROWS;
#pragma unroll
        for (int j = 0; j < 16; ++j) {
            int grow = m0 + wrow + (j >> 2) * 16 + quad * 4 + (j & 3);
            atomicAdd(&rp[grow], rs[j]);
        }
    }
}

// ---------------- final loss reduction ----------------

__global__ void loss_kernel(const float* __restrict__ rowsum, const float* __restrict__ selfdot,
                            const float* __restrict__ crossdot, float* __restrict__ out) {
    __shared__ float red[256];
    float acc = 0.f;
    for (int i = threadIdx.x; i < 3 * 2 * N_ROWS; i += 256) {
        float denom = rowsum[i] - __expf(2.f * selfdot[i]);
        acc += logf(denom) - 2.f * crossdot[i];
    }
    red[threadIdx.x] = acc;
    __syncthreads();
    for (int s = 128; s > 0; s >>= 1) {
        if (threadIdx.x < s) red[threadIdx.x] += red[threadIdx.x + s];
        __syncthreads();
    }
    if (threadIdx.x == 0) out[0] = red[0] * (1.f / 24576.f);
}

// ---------------- launch ----------------

extern "C" void kernel_launch(void* const* d_in, const int* in_sizes, int n_in,
                              void* d_out, int out_size, void* d_ws, size_t ws_size,
                              hipStream_t stream) {
    const float* doc0   = (const float*)d_in[0];
    const float* doc1   = (const float*)d_in[1];
    const float* doc2   = (const float*)d_in[2];
    const float* W1s    = (const float*)d_in[3];
    const float* b1s    = (const float*)d_in[4];
    const float* gammas = (const float*)d_in[5];
    const float* betas  = (const float*)d_in[6];
    const float* W2s    = (const float*)d_in[7];
    const float* b2s    = (const float*)d_in[8];
    float* out = (float*)d_out;

    char* base = (char*)d_ws;
    size_t off = 0;
    auto alloc = [&](size_t bytes) -> char* {
        char* r = base + off;
        off += (bytes + 255) & ~(size_t)255;
        return r;
    };

    unsigned short* Xb   = (unsigned short*)alloc((size_t)3 * N_ROWS * IN_DIM * 2);
    unsigned short* W1t  = (unsigned short*)alloc((size_t)6 * OUT_DIM * IN_DIM * 2);
    unsigned short* W2t  = (unsigned short*)alloc((size_t)6 * OUT_DIM * OUT_DIM * 2);
    float*          H    = (float*)         alloc((size_t)6 * N_ROWS * OUT_DIM * 4);
    unsigned short* Hb   = (unsigned short*)alloc((size_t)6 * N_ROWS * OUT_DIM * 2);
    unsigned short* Abuf = (unsigned short*)alloc((size_t)6 * N_ROWS * OUT_DIM * 2);
    float*          stats  = (float*)alloc((size_t)6 * OUT_DIM * 2 * 4);
    float*          rowsum = (float*)alloc((size_t)3 * 2 * N_ROWS * 4);
    float*          sdot   = (float*)alloc((size_t)3 * 2 * N_ROWS * 4);
    float*          cdot   = (float*)alloc((size_t)3 * 2 * N_ROWS * 4);

    if (ws_size < off) return;   // workspace too small — bench will flag; adapt next round

    hipMemsetAsync(stats, 0, (size_t)6 * OUT_DIM * 2 * 4, stream);
    hipMemsetAsync(rowsum, 0, (size_t)3 * 2 * N_ROWS * 4, stream);

    // convert inputs to bf16 (weights transposed to [N][K])
    conv_docs<<<(3 * N_ROWS * IN_DIM / 4 + 255) / 256, 256, 0, stream>>>(doc0, doc1, doc2, Xb);
    transpose_conv<<<dim3(OUT_DIM / 32, IN_DIM / 32, 6), dim3(32, 8), 0, stream>>>(W1s, W1t, IN_DIM, OUT_DIM);
    transpose_conv<<<dim3(OUT_DIM / 32, OUT_DIM / 32, 6), dim3(32, 8), 0, stream>>>(W2s, W2t, OUT_DIM, OUT_DIM);

    // GEMM1: H = doc @ W1 + b1   (6 projectors batched over z)
    gemm_bt_bias<<<dim3(OUT_DIM / BN, N_ROWS / BM, 6), 256, 0, stream>>>(
        Xb, (size_t)N_ROWS * IN_DIM, 1, W1t, b1s, H, N_ROWS, OUT_DIM, IN_DIM);

    bn_stats<<<dim3(OUT_DIM / 128, 8, 6), 128, 0, stream>>>(H, stats);
    bn_apply<<<(int)(((size_t)6 * N_ROWS * OUT_DIM + 255) / 256), 256, 0, stream>>>(H, stats, gammas, betas, Hb);

    // GEMM2: O = Hb @ W2 + b2  (reuse H buffer for O)
    gemm_bt_bias<<<dim3(OUT_DIM / BN, N_ROWS / BM, 6), 256, 0, stream>>>(
        Hb, (size_t)N_ROWS * OUT_DIM, 0, W2t, b2s, H, N_ROWS, OUT_DIM, OUT_DIM);

    l2norm<<<6 * N_ROWS / 4, 256, 0, stream>>>(H, Abuf);

    // fused Gram + exp + row-sum per pair
    gram_kernel<<<dim3(4, 64, 3), 256, 0, stream>>>(Abuf, rowsum, sdot, cdot);

    loss_kernel<<<1, 256, 0, stream>>>(rowsum, sdot, cdot, out);
}

// Round 2
// 472.507 us; speedup vs baseline: 1.5416x; 1.5416x over previous
//
#include <hip/hip_runtime.h>
#include <hip/hip_bf16.h>

#define N_ROWS 4096
#define IN_DIM 768
#define OUT_DIM 512

#define BM 128
#define BN 128
#define BK 64
// LDS tile: 128 rows x 64 bf16 cols, row stride 64 elems (128 B), XOR-swizzled
// 16B chunks: logical chunk lc of row r lives at physical chunk lc^(r&7).

using bf16x8 = __attribute__((ext_vector_type(8))) short;
using f32x4  = __attribute__((ext_vector_type(4))) float;

__device__ __constant__ int c_docmap[6] = {0, 1, 0, 2, 1, 2};

__device__ inline unsigned short f2bf(float f) {
    __hip_bfloat16 h = __float2bfloat16(f);
    return reinterpret_cast<unsigned short&>(h);
}

// ---------------- conversion kernels ----------------

__global__ void conv_docs(const float* __restrict__ d0, const float* __restrict__ d1,
                          const float* __restrict__ d2, unsigned short* __restrict__ Xb) {
    const size_t n1 = (size_t)N_ROWS * IN_DIM;
    size_t i = (size_t)blockIdx.x * blockDim.x + threadIdx.x;
    size_t idx = i * 4;
    if (idx >= 3 * n1) return;
    int d = (int)(idx / n1);
    size_t loc = idx - (size_t)d * n1;
    const float* src = (d == 0) ? d0 : ((d == 1) ? d1 : d2);
    float4 v = *(const float4*)(src + loc);
    ushort4 o;
    o.x = f2bf(v.x); o.y = f2bf(v.y); o.z = f2bf(v.z); o.w = f2bf(v.w);
    *(ushort4*)(Xb + idx) = o;
}

// in: [z][R][C] fp32  ->  out: [z][C][R] bf16
__global__ void transpose_conv(const float* __restrict__ in, unsigned short* __restrict__ out,
                               int R, int C) {
    __shared__ float tile[32][33];
    int z = blockIdx.z;
    const float* ip = in + (size_t)z * R * C;
    unsigned short* op = out + (size_t)z * R * C;
    int r0 = blockIdx.y * 32, c0 = blockIdx.x * 32;
    for (int j = threadIdx.y; j < 32; j += 8)
        tile[j][threadIdx.x] = ip[(size_t)(r0 + j) * C + c0 + threadIdx.x];
    __syncthreads();
    for (int j = threadIdx.y; j < 32; j += 8)
        op[(size_t)(c0 + j) * R + r0 + threadIdx.x] = f2bf(tile[threadIdx.x][j]);
}

// ---------------- async swizzled staging + MFMA step ----------------

// Stage 128 rows x 64 k-cols into lds (16 KB) via global_load_lds width-16.
// Each wave stages 32 rows (4 instrs x 8 rows). Swizzle applied on the GLOBAL
// source address (LDS dest is wave-uniform base + lane*16 by HW).
__device__ inline void stage_tile_async(const unsigned short* __restrict__ G, int ld,
                                        int row0, int k0, unsigned short* lds,
                                        int wave, int lane) {
    int rbase = wave * 32;
#pragma unroll
    for (int i = 0; i < 4; ++i) {
        int rs = rbase + i * 8;                 // wave-uniform
        int r  = rs + (lane >> 3);
        int pc = lane & 7;                      // physical chunk this lane fills
        int lc = pc ^ (r & 7);                  // logical chunk to fetch
        const unsigned short* g = G + (size_t)(row0 + r) * ld + k0 + lc * 8;
        unsigned short* l = lds + rs * 64;      // wave-uniform LDS base
        __builtin_amdgcn_global_load_lds(
            (const __attribute__((address_space(1))) unsigned int*)g,
            (__attribute__((address_space(3))) unsigned int*)l, 16, 0, 0);
    }
}

__device__ inline void mfma_step_swz(const unsigned short* As, const unsigned short* Bs,
                                     int wrow, int wcol, int lane15, int quad,
                                     f32x4 acc[4][4]) {
#pragma unroll
    for (int kk = 0; kk < BK; kk += 32) {
        int lcb = (kk >> 3) + quad;             // logical chunk for this frag
        bf16x8 aF[4], bF[4];
#pragma unroll
        for (int t = 0; t < 4; ++t) {
            int row = wrow + t * 16 + lane15;
            aF[t] = *(const bf16x8*)(As + row * 64 + ((lcb ^ (row & 7)) * 8));
        }
#pragma unroll
        for (int t = 0; t < 4; ++t) {
            int row = wcol + t * 16 + lane15;
            bF[t] = *(const bf16x8*)(Bs + row * 64 + ((lcb ^ (row & 7)) * 8));
        }
#pragma unroll
        for (int mt = 0; mt < 4; ++mt)
#pragma unroll
            for (int nt = 0; nt < 4; ++nt)
                acc[mt][nt] = __builtin_amdgcn_mfma_f32_16x16x32_bf16(aF[mt], bF[nt], acc[mt][nt], 0, 0, 0);
    }
}

// ---------------- projector GEMM (B^T form) ----------------

__global__ __launch_bounds__(256) void gemm_bt_bias(
    const unsigned short* __restrict__ Abase, size_t aStride, int useMap,
    const unsigned short* __restrict__ Bbase, const float* __restrict__ biasAll,
    float* __restrict__ Cbase, int M, int N, int K) {
    int z = blockIdx.z;
    const unsigned short* A = Abase + (useMap ? (size_t)c_docmap[z] : (size_t)z) * aStride;
    const unsigned short* B = Bbase + (size_t)z * (size_t)N * K;
    const float* bz = biasAll + (size_t)z * N;
    float* C = Cbase + (size_t)z * (size_t)M * N;

    int m0 = blockIdx.y * BM, n0 = blockIdx.x * BN;
    int tid = threadIdx.x;
    int wave = tid >> 6, lane = tid & 63;
    int lane15 = lane & 15, quad = lane >> 4;
    int wrow = (wave >> 1) * 64, wcol = (wave & 1) * 64;

    __shared__ unsigned short As[BM * 64];
    __shared__ unsigned short Bs[BN * 64];

    f32x4 acc[4][4];
#pragma unroll
    for (int mt = 0; mt < 4; ++mt)
#pragma unroll
        for (int nt = 0; nt < 4; ++nt)
            acc[mt][nt] = (f32x4){0.f, 0.f, 0.f, 0.f};

    for (int k0 = 0; k0 < K; k0 += BK) {
        stage_tile_async(A, K, m0, k0, As, wave, lane);
        stage_tile_async(B, K, n0, k0, Bs, wave, lane);
        __syncthreads();
        mfma_step_swz(As, Bs, wrow, wcol, lane15, quad, acc);
        __syncthreads();
    }

#pragma unroll
    for (int mt = 0; mt < 4; ++mt)
#pragma unroll
        for (int nt = 0; nt < 4; ++nt) {
            int col = n0 + wcol + nt * 16 + lane15;
            float bv = bz[col];
#pragma unroll
            for (int r = 0; r < 4; ++r) {
                int row = m0 + wrow + mt * 16 + quad * 4 + r;
                C[(size_t)row * N + col] = acc[mt][nt][r] + bv;
            }
        }
}

// ---------------- BN stats / apply ----------------

__global__ void bn_stats(const float* __restrict__ H, float* __restrict__ stats) {
    int k = blockIdx.z;
    int c = blockIdx.x * 128 + threadIdx.x;
    int r0 = blockIdx.y * 512;
    const float* Hp = H + (size_t)k * N_ROWS * OUT_DIM;
    float s1 = 0.f, s2 = 0.f;
    for (int r = r0; r < r0 + 512; ++r) {
        float v = Hp[(size_t)r * OUT_DIM + c];
        s1 += v; s2 += v * v;
    }
    atomicAdd(&stats[((size_t)k * OUT_DIM + c) * 2 + 0], s1);
    atomicAdd(&stats[((size_t)k * OUT_DIM + c) * 2 + 1], s2);
}

__global__ void bn_apply(const float* __restrict__ H, const float* __restrict__ stats,
                         const float* __restrict__ gammas, const float* __restrict__ betas,
                         unsigned short* __restrict__ Hb) {
    size_t i = (size_t)blockIdx.x * blockDim.x + threadIdx.x;
    if (i >= (size_t)6 * N_ROWS * OUT_DIM) return;
    int c = (int)(i % OUT_DIM);
    int k = (int)(i / ((size_t)N_ROWS * OUT_DIM));
    size_t sc = (size_t)k * OUT_DIM + c;
    float s1 = stats[sc * 2 + 0], s2 = stats[sc * 2 + 1];
    float mu = s1 * (1.f / N_ROWS);
    float var = s2 * (1.f / N_ROWS) - mu * mu;
    float g = gammas[sc], b = betas[sc];
    float v = (H[i] - mu) * rsqrtf(var + 1e-5f) * g + b;
    v = fmaxf(v, 0.f);
    Hb[i] = f2bf(v);
}

// ---------------- row L2 norm -> bf16 ----------------

__global__ __launch_bounds__(256) void l2norm(const float* __restrict__ O,
                                              unsigned short* __restrict__ A) {
    int wave = threadIdx.x >> 6, lane = threadIdx.x & 63;
    int row = blockIdx.x * 4 + wave;
    const float* Op = O + (size_t)row * OUT_DIM;
    float4 v0 = *(const float4*)(Op + lane * 8);
    float4 v1 = *(const float4*)(Op + lane * 8 + 4);
    float ss = v0.x * v0.x + v0.y * v0.y + v0.z * v0.z + v0.w * v0.w
             + v1.x * v1.x + v1.y * v1.y + v1.z * v1.z + v1.w * v1.w;
#pragma unroll
    for (int m = 1; m < 64; m <<= 1) ss += __shfl_xor(ss, m);
    float nrm = sqrtf(ss);
    float sc = 1.f / fmaxf(nrm, 1e-12f);
    unsigned short* Ap = A + (size_t)row * OUT_DIM + lane * 8;
    ushort4 o0, o1;
    o0.x = f2bf(v0.x * sc); o0.y = f2bf(v0.y * sc); o0.z = f2bf(v0.z * sc); o0.w = f2bf(v0.w * sc);
    o1.x = f2bf(v1.x * sc); o1.y = f2bf(v1.y * sc); o1.z = f2bf(v1.z * sc); o1.w = f2bf(v1.w * sc);
    *(ushort4*)(Ap) = o0;
    *(ushort4*)(Ap + 4) = o1;
}

// ---------------- symmetric fused Gram + exp + row/col-sum ----------------

// Per pair p: Cm = [o1;o2] is [8192][512] bf16 L2-normalized.
// Enumerate tile pairs (I<=J) of 128 rows each (64 tiles -> 2080 blocks/pair).
// Off-diag tile: exp(2s) accumulates into rowsum[rows of I] (row sums) AND
// rowsum[rows of J] (col sums). Diag tile: row sums only. selfdot on diag
// tiles; crossdot on J==I+32 tiles (j = i + 4096).
__global__ __launch_bounds__(256) void gram_kernel(const unsigned short* __restrict__ Abase,
                                                   float* __restrict__ rowsum,
                                                   float* __restrict__ selfdot,
                                                   float* __restrict__ crossdot) {
    const int K = OUT_DIM;
    int p = blockIdx.z;
    const unsigned short* Cm = Abase + (size_t)p * 2 * N_ROWS * OUT_DIM;

    // decode upper-triangular (I,J) from blockIdx.x in [0,2080)
    int idx = blockIdx.x, I = 0;
    while (true) { int cnt = 64 - I; if (idx < cnt) break; idx -= cnt; ++I; }
    int J = I + idx;
    int m0 = I * BM, n0 = J * BM;
    bool isDiag  = (I == J);
    bool isCross = (J == I + N_ROWS / BM);

    int tid = threadIdx.x;
    int wave = tid >> 6, lane = tid & 63;
    int lane15 = lane & 15, quad = lane >> 4;
    int wrow = (wave >> 1) * 64, wcol = (wave & 1) * 64;

    __shared__ unsigned short As[BM * 64];
    __shared__ unsigned short Bs[BM * 64];

    f32x4 acc[4][4];
#pragma unroll
    for (int mt = 0; mt < 4; ++mt)
#pragma unroll
        for (int nt = 0; nt < 4; ++nt)
            acc[mt][nt] = (f32x4){0.f, 0.f, 0.f, 0.f};

    for (int k0 = 0; k0 < K; k0 += BK) {
        stage_tile_async(Cm, K, m0, k0, As, wave, lane);
        if (!isDiag) stage_tile_async(Cm, K, n0, k0, Bs, wave, lane);
        __syncthreads();
        mfma_step_swz(As, isDiag ? As : Bs, wrow, wcol, lane15, quad, acc);
        __syncthreads();
    }

    float* sdp = selfdot + (size_t)p * 2 * N_ROWS;
    float* cdp = crossdot + (size_t)p * 2 * N_ROWS;
    float* rp  = rowsum  + (size_t)p * 2 * N_ROWS;

    float rs[16];
    float cs[4];
#pragma unroll
    for (int j = 0; j < 16; ++j) rs[j] = 0.f;
#pragma unroll
    for (int j = 0; j < 4; ++j) cs[j] = 0.f;

#pragma unroll
    for (int mt = 0; mt < 4; ++mt)
#pragma unroll
        for (int nt = 0; nt < 4; ++nt) {
            int gcol = n0 + wcol + nt * 16 + lane15;
#pragma unroll
            for (int r = 0; r < 4; ++r) {
                int grow = m0 + wrow + mt * 16 + quad * 4 + r;
                float s = acc[mt][nt][r];
                float e = __expf(2.f * s);
                rs[mt * 4 + r] += e;
                cs[nt] += e;
                if (isDiag && gcol == grow) sdp[grow] = s;
                if (isCross && gcol == grow + N_ROWS) { cdp[grow] = s; cdp[gcol] = s; }
            }
        }

    // row sums: reduce across lane15 (xor 1,2,4,8)
#pragma unroll
    for (int j = 0; j < 16; ++j) {
        float v = rs[j];
        v += __shfl_xor(v, 1);
        v += __shfl_xor(v, 2);
        v += __shfl_xor(v, 4);
        v += __shfl_xor(v, 8);
        rs[j] = v;
    }
    if (lane15 == 0) {
#pragma unroll
        for (int j = 0; j < 16; ++j) {
            int grow = m0 + wrow + (j >> 2) * 16 + quad * 4 + (j & 3);
            atomicAdd(&rp[grow], rs[j]);
        }
    }

    // col sums (off-diag only): reduce across quad (xor 16,32)
    if (!isDiag) {
#pragma unroll
        for (int n = 0; n < 4; ++n) {
            float v = cs[n];
            v += __shfl_xor(v, 16);
            v += __shfl_xor(v, 32);
            cs[n] = v;
        }
        if (quad == 0) {
#pragma unroll
            for (int n = 0; n < 4; ++n) {
                int gcol = n0 + wcol + n * 16 + lane15;
                atomicAdd(&rp[gcol], cs[n]);
            }
        }
    }
}

// ---------------- final loss reduction ----------------

__global__ void loss_kernel(const float* __restrict__ rowsum, const float* __restrict__ selfdot,
                            const float* __restrict__ crossdot, float* __restrict__ out) {
    __shared__ float red[256];
    float acc = 0.f;
    for (int i = threadIdx.x; i < 3 * 2 * N_ROWS; i += 256) {
        float denom = rowsum[i] - __expf(2.f * selfdot[i]);
        acc += logf(denom) - 2.f * crossdot[i];
    }
    red[threadIdx.x] = acc;
    __syncthreads();
    for (int s = 128; s > 0; s >>= 1) {
        if (threadIdx.x < s) red[threadIdx.x] += red[threadIdx.x + s];
        __syncthreads();
    }
    if (threadIdx.x == 0) out[0] = red[0] * (1.f / 24576.f);
}

// ---------------- launch ----------------

extern "C" void kernel_launch(void* const* d_in, const int* in_sizes, int n_in,
                              void* d_out, int out_size, void* d_ws, size_t ws_size,
                              hipStream_t stream) {
    const float* doc0   = (const float*)d_in[0];
    const float* doc1   = (const float*)d_in[1];
    const float* doc2   = (const float*)d_in[2];
    const float* W1s    = (const float*)d_in[3];
    const float* b1s    = (const float*)d_in[4];
    const float* gammas = (const float*)d_in[5];
    const float* betas  = (const float*)d_in[6];
    const float* W2s    = (const float*)d_in[7];
    const float* b2s    = (const float*)d_in[8];
    float* out = (float*)d_out;

    char* base = (char*)d_ws;
    size_t off = 0;
    auto alloc = [&](size_t bytes) -> char* {
        char* r = base + off;
        off += (bytes + 255) & ~(size_t)255;
        return r;
    };

    unsigned short* Xb   = (unsigned short*)alloc((size_t)3 * N_ROWS * IN_DIM * 2);
    unsigned short* W1t  = (unsigned short*)alloc((size_t)6 * OUT_DIM * IN_DIM * 2);
    unsigned short* W2t  = (unsigned short*)alloc((size_t)6 * OUT_DIM * OUT_DIM * 2);
    float*          H    = (float*)         alloc((size_t)6 * N_ROWS * OUT_DIM * 4);
    unsigned short* Hb   = (unsigned short*)alloc((size_t)6 * N_ROWS * OUT_DIM * 2);
    unsigned short* Abuf = (unsigned short*)alloc((size_t)6 * N_ROWS * OUT_DIM * 2);
    float*          stats  = (float*)alloc((size_t)6 * OUT_DIM * 2 * 4);
    float*          rowsum = (float*)alloc((size_t)3 * 2 * N_ROWS * 4);
    float*          sdot   = (float*)alloc((size_t)3 * 2 * N_ROWS * 4);
    float*          cdot   = (float*)alloc((size_t)3 * 2 * N_ROWS * 4);

    if (ws_size < off) return;

    hipMemsetAsync(stats, 0, (size_t)6 * OUT_DIM * 2 * 4, stream);
    hipMemsetAsync(rowsum, 0, (size_t)3 * 2 * N_ROWS * 4, stream);

    conv_docs<<<(3 * N_ROWS * IN_DIM / 4 + 255) / 256, 256, 0, stream>>>(doc0, doc1, doc2, Xb);
    transpose_conv<<<dim3(OUT_DIM / 32, IN_DIM / 32, 6), dim3(32, 8), 0, stream>>>(W1s, W1t, IN_DIM, OUT_DIM);
    transpose_conv<<<dim3(OUT_DIM / 32, OUT_DIM / 32, 6), dim3(32, 8), 0, stream>>>(W2s, W2t, OUT_DIM, OUT_DIM);

    gemm_bt_bias<<<dim3(OUT_DIM / BN, N_ROWS / BM, 6), 256, 0, stream>>>(
        Xb, (size_t)N_ROWS * IN_DIM, 1, W1t, b1s, H, N_ROWS, OUT_DIM, IN_DIM);

    bn_stats<<<dim3(OUT_DIM / 128, 8, 6), 128, 0, stream>>>(H, stats);
    bn_apply<<<(int)(((size_t)6 * N_ROWS * OUT_DIM + 255) / 256), 256, 0, stream>>>(H, stats, gammas, betas, Hb);

    gemm_bt_bias<<<dim3(OUT_DIM / BN, N_ROWS / BM, 6), 256, 0, stream>>>(
        Hb, (size_t)N_ROWS * OUT_DIM, 0, W2t, b2s, H, N_ROWS, OUT_DIM, OUT_DIM);

    l2norm<<<6 * N_ROWS / 4, 256, 0, stream>>>(H, Abuf);

    // symmetric gram: 64*65/2 = 2080 tile-pairs per pair, 3 pairs
    gram_kernel<<<dim3(2080, 1, 3), 256, 0, stream>>>(Abuf, rowsum, sdot, cdot);

    loss_kernel<<<1, 256, 0, stream>>>(rowsum, sdot, cdot, out);
}

// Round 3
// 426.301 us; speedup vs baseline: 1.7087x; 1.1084x over previous
//
#include <hip/hip_runtime.h>
#include <hip/hip_bf16.h>

#define N_ROWS 4096
#define IN_DIM 768
#define OUT_DIM 512

#define BM 128
#define BN 128
#define BK 64
// LDS tiles: rows x 64 bf16 cols, row stride 64 elems (128 B), XOR-swizzled:
// 16B chunk lc of row r lives at physical chunk lc^(r&7). Measured 0 conflicts (R2).

using bf16x8 = __attribute__((ext_vector_type(8))) short;
using f32x4  = __attribute__((ext_vector_type(4))) float;

__device__ __constant__ int c_docmap[6] = {0, 1, 0, 2, 1, 2};

__device__ inline unsigned short f2bf(float f) {
    __hip_bfloat16 h = __float2bfloat16(f);
    return reinterpret_cast<unsigned short&>(h);
}
__device__ inline float bf2f(unsigned short u) {
    return __uint_as_float((unsigned int)u << 16);
}

// ---------------- conversion kernels ----------------

__global__ void conv_docs(const float* __restrict__ d0, const float* __restrict__ d1,
                          const float* __restrict__ d2, unsigned short* __restrict__ Xb) {
    const size_t n1 = (size_t)N_ROWS * IN_DIM;
    size_t i = (size_t)blockIdx.x * blockDim.x + threadIdx.x;
    size_t idx = i * 4;
    if (idx >= 3 * n1) return;
    int d = (int)(idx / n1);
    size_t loc = idx - (size_t)d * n1;
    const float* src = (d == 0) ? d0 : ((d == 1) ? d1 : d2);
    float4 v = *(const float4*)(src + loc);
    ushort4 o;
    o.x = f2bf(v.x); o.y = f2bf(v.y); o.z = f2bf(v.z); o.w = f2bf(v.w);
    *(ushort4*)(Xb + idx) = o;
}

__global__ void transpose_conv(const float* __restrict__ in, unsigned short* __restrict__ out,
                               int R, int C) {
    __shared__ float tile[32][33];
    int z = blockIdx.z;
    const float* ip = in + (size_t)z * R * C;
    unsigned short* op = out + (size_t)z * R * C;
    int r0 = blockIdx.y * 32, c0 = blockIdx.x * 32;
    for (int j = threadIdx.y; j < 32; j += 8)
        tile[j][threadIdx.x] = ip[(size_t)(r0 + j) * C + c0 + threadIdx.x];
    __syncthreads();
    for (int j = threadIdx.y; j < 32; j += 8)
        op[(size_t)(c0 + j) * R + r0 + threadIdx.x] = f2bf(tile[threadIdx.x][j]);
}

// ---------------- async swizzled staging ----------------

// 4-wave version: 128 rows x 64 cols (for 256-thread GEMMs)
__device__ inline void stage_tile_async(const unsigned short* __restrict__ G, int ld,
                                        int row0, int k0, unsigned short* lds,
                                        int wave, int lane) {
    int rbase = wave * 32;
#pragma unroll
    for (int i = 0; i < 4; ++i) {
        int rs = rbase + i * 8;
        int r  = rs + (lane >> 3);
        int pc = lane & 7;
        int lc = pc ^ (r & 7);
        const unsigned short* g = G + (size_t)(row0 + r) * ld + k0 + lc * 8;
        unsigned short* l = lds + rs * 64;
        __builtin_amdgcn_global_load_lds(
            (const __attribute__((address_space(1))) unsigned int*)g,
            (__attribute__((address_space(3))) unsigned int*)l, 16, 0, 0);
    }
}

// 8-wave version: 256 rows x 64 cols (for 512-thread gram)
__device__ inline void stage512(const unsigned short* __restrict__ G, int ld,
                                int row0, int k0, unsigned short* lds,
                                int wave, int lane) {
    int rbase = wave * 32;
#pragma unroll
    for (int i = 0; i < 4; ++i) {
        int rs = rbase + i * 8;
        int r  = rs + (lane >> 3);
        int pc = lane & 7;
        int lc = pc ^ (r & 7);
        const unsigned short* g = G + (size_t)(row0 + r) * ld + k0 + lc * 8;
        unsigned short* l = lds + rs * 64;
        __builtin_amdgcn_global_load_lds(
            (const __attribute__((address_space(1))) unsigned int*)g,
            (__attribute__((address_space(3))) unsigned int*)l, 16, 0, 0);
    }
}

__device__ inline void mfma_step_swz(const unsigned short* As, const unsigned short* Bs,
                                     int wrow, int wcol, int lane15, int quad,
                                     f32x4 acc[4][4]) {
#pragma unroll
    for (int kk = 0; kk < BK; kk += 32) {
        int lcb = (kk >> 3) + quad;
        bf16x8 aF[4], bF[4];
#pragma unroll
        for (int t = 0; t < 4; ++t) {
            int row = wrow + t * 16 + lane15;
            aF[t] = *(const bf16x8*)(As + row * 64 + ((lcb ^ (row & 7)) * 8));
        }
#pragma unroll
        for (int t = 0; t < 4; ++t) {
            int row = wcol + t * 16 + lane15;
            bF[t] = *(const bf16x8*)(Bs + row * 64 + ((lcb ^ (row & 7)) * 8));
        }
#pragma unroll
        for (int mt = 0; mt < 4; ++mt)
#pragma unroll
            for (int nt = 0; nt < 4; ++nt)
                acc[mt][nt] = __builtin_amdgcn_mfma_f32_16x16x32_bf16(aF[mt], bF[nt], acc[mt][nt], 0, 0, 0);
    }
}

// ---------------- GEMM1: X @ W1^T + b1, fused BN-stats, bf16 out ----------------

__global__ __launch_bounds__(256) void gemm1_bn(
    const unsigned short* __restrict__ Xb, const unsigned short* __restrict__ W1t,
    const float* __restrict__ biasAll, unsigned short* __restrict__ Hb,
    float* __restrict__ stats) {
    int z = blockIdx.z;
    const unsigned short* A = Xb + (size_t)c_docmap[z] * N_ROWS * IN_DIM;
    const unsigned short* B = W1t + (size_t)z * OUT_DIM * IN_DIM;
    const float* bz = biasAll + (size_t)z * OUT_DIM;
    unsigned short* C = Hb + (size_t)z * N_ROWS * OUT_DIM;

    int m0 = blockIdx.y * BM, n0 = blockIdx.x * BN;
    int tid = threadIdx.x;
    int wave = tid >> 6, lane = tid & 63;
    int lane15 = lane & 15, quad = lane >> 4;
    int wrow = (wave >> 1) * 64, wcol = (wave & 1) * 64;

    __shared__ unsigned short As[BM * 64];
    __shared__ unsigned short Bs[BN * 64];

    f32x4 acc[4][4];
#pragma unroll
    for (int mt = 0; mt < 4; ++mt)
#pragma unroll
        for (int nt = 0; nt < 4; ++nt)
            acc[mt][nt] = (f32x4){0.f, 0.f, 0.f, 0.f};

    for (int k0 = 0; k0 < IN_DIM; k0 += BK) {
        stage_tile_async(A, IN_DIM, m0, k0, As, wave, lane);
        stage_tile_async(B, IN_DIM, n0, k0, Bs, wave, lane);
        __syncthreads();
        mfma_step_swz(As, Bs, wrow, wcol, lane15, quad, acc);
        __syncthreads();
    }

    float s1[4] = {0.f, 0.f, 0.f, 0.f}, s2[4] = {0.f, 0.f, 0.f, 0.f};
#pragma unroll
    for (int nt = 0; nt < 4; ++nt) {
        int col = n0 + wcol + nt * 16 + lane15;
        float bv = bz[col];
#pragma unroll
        for (int mt = 0; mt < 4; ++mt)
#pragma unroll
            for (int r = 0; r < 4; ++r) {
                int row = m0 + wrow + mt * 16 + quad * 4 + r;
                float v = acc[mt][nt][r] + bv;
                C[(size_t)row * OUT_DIM + col] = f2bf(v);
                s1[nt] += v; s2[nt] += v * v;
            }
    }
#pragma unroll
    for (int nt = 0; nt < 4; ++nt) {
        float a = s1[nt], b = s2[nt];
        a += __shfl_xor(a, 16); a += __shfl_xor(a, 32);
        b += __shfl_xor(b, 16); b += __shfl_xor(b, 32);
        if (quad == 0) {
            int col = n0 + wcol + nt * 16 + lane15;
            atomicAdd(&stats[((size_t)z * OUT_DIM + col) * 2 + 0], a);
            atomicAdd(&stats[((size_t)z * OUT_DIM + col) * 2 + 1], b);
        }
    }
}

// ---------------- BN apply + ReLU (in place, bf16) ----------------

__global__ void bn_apply(unsigned short* __restrict__ Hb, const float* __restrict__ stats,
                         const float* __restrict__ gammas, const float* __restrict__ betas) {
    size_t i4 = ((size_t)blockIdx.x * blockDim.x + threadIdx.x) * 4;
    if (i4 >= (size_t)6 * N_ROWS * OUT_DIM) return;
    int c = (int)(i4 % OUT_DIM);
    int k = (int)(i4 / ((size_t)N_ROWS * OUT_DIM));
    ushort4 h = *(ushort4*)(Hb + i4);
    unsigned short hv[4] = {h.x, h.y, h.z, h.w};
    ushort4 o;
    unsigned short* ov = (unsigned short*)&o;
#pragma unroll
    for (int j = 0; j < 4; ++j) {
        size_t sc = (size_t)k * OUT_DIM + c + j;
        float mu = stats[sc * 2 + 0] * (1.f / N_ROWS);
        float var = stats[sc * 2 + 1] * (1.f / N_ROWS) - mu * mu;
        float v = (bf2f(hv[j]) - mu) * rsqrtf(var + 1e-5f) * gammas[sc] + betas[sc];
        ov[j] = f2bf(fmaxf(v, 0.f));
    }
    *(ushort4*)(Hb + i4) = o;
}

// ---------------- GEMM2: H @ W2^T + b2, fused row-sumsq, bf16 out ----------------

__global__ __launch_bounds__(256) void gemm2_norm(
    const unsigned short* __restrict__ Hb, const unsigned short* __restrict__ W2t,
    const float* __restrict__ biasAll, unsigned short* __restrict__ O,
    float* __restrict__ rowsumsq) {
    int z = blockIdx.z;
    const unsigned short* A = Hb + (size_t)z * N_ROWS * OUT_DIM;
    const unsigned short* B = W2t + (size_t)z * OUT_DIM * OUT_DIM;
    const float* bz = biasAll + (size_t)z * OUT_DIM;
    unsigned short* C = O + (size_t)z * N_ROWS * OUT_DIM;
    float* rq = rowsumsq + (size_t)z * N_ROWS;

    int m0 = blockIdx.y * BM, n0 = blockIdx.x * BN;
    int tid = threadIdx.x;
    int wave = tid >> 6, lane = tid & 63;
    int lane15 = lane & 15, quad = lane >> 4;
    int wrow = (wave >> 1) * 64, wcol = (wave & 1) * 64;

    __shared__ unsigned short As[BM * 64];
    __shared__ unsigned short Bs[BN * 64];

    f32x4 acc[4][4];
#pragma unroll
    for (int mt = 0; mt < 4; ++mt)
#pragma unroll
        for (int nt = 0; nt < 4; ++nt)
            acc[mt][nt] = (f32x4){0.f, 0.f, 0.f, 0.f};

    for (int k0 = 0; k0 < OUT_DIM; k0 += BK) {
        stage_tile_async(A, OUT_DIM, m0, k0, As, wave, lane);
        stage_tile_async(B, OUT_DIM, n0, k0, Bs, wave, lane);
        __syncthreads();
        mfma_step_swz(As, Bs, wrow, wcol, lane15, quad, acc);
        __syncthreads();
    }

    float rs[16];
#pragma unroll
    for (int j = 0; j < 16; ++j) rs[j] = 0.f;
#pragma unroll
    for (int nt = 0; nt < 4; ++nt) {
        int col = n0 + wcol + nt * 16 + lane15;
        float bv = bz[col];
#pragma unroll
        for (int mt = 0; mt < 4; ++mt)
#pragma unroll
            for (int r = 0; r < 4; ++r) {
                int row = m0 + wrow + mt * 16 + quad * 4 + r;
                float v = acc[mt][nt][r] + bv;
                C[(size_t)row * OUT_DIM + col] = f2bf(v);
                rs[mt * 4 + r] += v * v;
            }
    }
#pragma unroll
    for (int j = 0; j < 16; ++j) {
        float v = rs[j];
        v += __shfl_xor(v, 1); v += __shfl_xor(v, 2);
        v += __shfl_xor(v, 4); v += __shfl_xor(v, 8);
        if (lane15 == 0) {
            int row = m0 + wrow + (j >> 2) * 16 + quad * 4 + (j & 3);
            atomicAdd(&rq[row], v);
        }
    }
}

// ---------------- row L2 norm (bf16 in/out, precomputed sumsq) ----------------

__global__ __launch_bounds__(256) void l2norm(const unsigned short* __restrict__ O,
                                              const float* __restrict__ rowsumsq,
                                              unsigned short* __restrict__ A) {
    int wave = threadIdx.x >> 6, lane = threadIdx.x & 63;
    int row = blockIdx.x * 4 + wave;    // 6*4096 rows
    float ss = rowsumsq[row];
    float sc = 1.f / fmaxf(sqrtf(ss), 1e-12f);
    const unsigned short* Op = O + (size_t)row * OUT_DIM + lane * 8;
    uint4 u = *(const uint4*)Op;
    unsigned int w[4] = {u.x, u.y, u.z, u.w};
    ushort4 o0, o1;
    unsigned short* ov = (unsigned short*)&o0;
#pragma unroll
    for (int j = 0; j < 8; ++j) {
        unsigned short us = (j & 1) ? (unsigned short)(w[j >> 1] >> 16)
                                    : (unsigned short)(w[j >> 1] & 0xffff);
        ov[j] = f2bf(bf2f(us) * sc);   // ov spans o0..o1 (8 contiguous ushorts)
    }
    unsigned short* Ap = A + (size_t)row * OUT_DIM + lane * 8;
    *(ushort4*)(Ap) = o0;
    *(ushort4*)(Ap + 4) = o1;
}

// ---------------- symmetric Gram, 256x256 super-tile, double-buffered ----------------

// Per pair p: Cm = [o1;o2] is [8192][512] bf16 L2-normalized.
// Supertiles of 256 rows: T=32, enumerate I<=J: 528 blocks per pair.
// 512 threads = 8 waves (2x4): each wave 128x64 output (8x4 frags).
__global__ __launch_bounds__(512, 2) void gram_kernel(const unsigned short* __restrict__ Abase,
                                                      float* __restrict__ rowsum,
                                                      float* __restrict__ selfdot,
                                                      float* __restrict__ crossdot) {
    int p = blockIdx.z;
    const unsigned short* Cm = Abase + (size_t)p * 2 * N_ROWS * OUT_DIM;

    int idx = blockIdx.x, I = 0;
    while (idx >= 32 - I) { idx -= 32 - I; ++I; }
    int J = I + idx;
    int m0 = I * 256, n0 = J * 256;
    bool isDiag  = (I == J);
    bool isCross = (J == I + 16);

    int tid = threadIdx.x;
    int wave = tid >> 6, lane = tid & 63;
    int lane15 = lane & 15, quad = lane >> 4;
    int wrow = (wave >> 2) * 128, wcol = (wave & 3) * 64;

    __shared__ unsigned short As0[256 * 64];
    __shared__ unsigned short As1[256 * 64];
    __shared__ unsigned short Bs0[256 * 64];
    __shared__ unsigned short Bs1[256 * 64];

    f32x4 acc[8][4];
#pragma unroll
    for (int mt = 0; mt < 8; ++mt)
#pragma unroll
        for (int nt = 0; nt < 4; ++nt)
            acc[mt][nt] = (f32x4){0.f, 0.f, 0.f, 0.f};

    stage512(Cm, OUT_DIM, m0, 0, As0, wave, lane);
    if (!isDiag) stage512(Cm, OUT_DIM, n0, 0, Bs0, wave, lane);
    __syncthreads();

#pragma unroll
    for (int k0 = 0; k0 < 8; ++k0) {
        const unsigned short* Acur = (k0 & 1) ? As1 : As0;
        const unsigned short* Bcur = isDiag ? Acur : ((k0 & 1) ? Bs1 : Bs0);
        unsigned short* Anxt = (k0 & 1) ? As0 : As1;
        unsigned short* Bnxt = (k0 & 1) ? Bs0 : Bs1;
        if (k0 < 7) {
            stage512(Cm, OUT_DIM, m0, (k0 + 1) * BK, Anxt, wave, lane);
            if (!isDiag) stage512(Cm, OUT_DIM, n0, (k0 + 1) * BK, Bnxt, wave, lane);
        }
#pragma unroll
        for (int kk = 0; kk < BK; kk += 32) {
            int lcb = (kk >> 3) + quad;
            bf16x8 aF[8], bF[4];
#pragma unroll
            for (int t = 0; t < 8; ++t) {
                int row = wrow + t * 16 + lane15;
                aF[t] = *(const bf16x8*)(Acur + row * 64 + ((lcb ^ (row & 7)) * 8));
            }
#pragma unroll
            for (int t = 0; t < 4; ++t) {
                int row = wcol + t * 16 + lane15;
                bF[t] = *(const bf16x8*)(Bcur + row * 64 + ((lcb ^ (row & 7)) * 8));
            }
#pragma unroll
            for (int mt = 0; mt < 8; ++mt)
#pragma unroll
                for (int nt = 0; nt < 4; ++nt)
                    acc[mt][nt] = __builtin_amdgcn_mfma_f32_16x16x32_bf16(aF[mt], bF[nt], acc[mt][nt], 0, 0, 0);
        }
        __syncthreads();
    }

    float* sdp = selfdot + (size_t)p * 2 * N_ROWS;
    float* cdp = crossdot + (size_t)p * 2 * N_ROWS;
    float* rp  = rowsum  + (size_t)p * 2 * N_ROWS;

    float rs[32];
    float cs[4];
#pragma unroll
    for (int j = 0; j < 32; ++j) rs[j] = 0.f;
#pragma unroll
    for (int j = 0; j < 4; ++j) cs[j] = 0.f;

#pragma unroll
    for (int mt = 0; mt < 8; ++mt)
#pragma unroll
        for (int nt = 0; nt < 4; ++nt) {
            int gcol = n0 + wcol + nt * 16 + lane15;
#pragma unroll
            for (int r = 0; r < 4; ++r) {
                int grow = m0 + wrow + mt * 16 + quad * 4 + r;
                float s = acc[mt][nt][r];
                float e = __expf(2.f * s);
                rs[mt * 4 + r] += e;
                cs[nt] += e;
                if (isDiag && gcol == grow) sdp[grow] = s;
                if (isCross && gcol == grow + N_ROWS) { cdp[grow] = s; cdp[gcol] = s; }
            }
        }

#pragma unroll
    for (int j = 0; j < 32; ++j) {
        float v = rs[j];
        v += __shfl_xor(v, 1); v += __shfl_xor(v, 2);
        v += __shfl_xor(v, 4); v += __shfl_xor(v, 8);
        rs[j] = v;
    }
    if (lane15 == 0) {
#pragma unroll
        for (int j = 0; j < 32; ++j) {
            int grow = m0 + wrow + (j >> 2) * 16 + quad * 4 + (j & 3);
            atomicAdd(&rp[grow], rs[j]);
        }
    }

    if (!isDiag) {
#pragma unroll
        for (int n = 0; n < 4; ++n) {
            float v = cs[n];
            v += __shfl_xor(v, 16); v += __shfl_xor(v, 32);
            cs[n] = v;
        }
        if (quad == 0) {
#pragma unroll
            for (int n = 0; n < 4; ++n) {
                int gcol = n0 + wcol + n * 16 + lane15;
                atomicAdd(&rp[gcol], cs[n]);
            }
        }
    }
}

// ---------------- final loss reduction ----------------

__global__ void loss_kernel(const float* __restrict__ rowsum, const float* __restrict__ selfdot,
                            const float* __restrict__ crossdot, float* __restrict__ out) {
    __shared__ float red[256];
    float acc = 0.f;
    for (int i = threadIdx.x; i < 3 * 2 * N_ROWS; i += 256) {
        float denom = rowsum[i] - __expf(2.f * selfdot[i]);
        acc += logf(denom) - 2.f * crossdot[i];
    }
    red[threadIdx.x] = acc;
    __syncthreads();
    for (int s = 128; s > 0; s >>= 1) {
        if (threadIdx.x < s) red[threadIdx.x] += red[threadIdx.x + s];
        __syncthreads();
    }
    if (threadIdx.x == 0) out[0] = red[0] * (1.f / 24576.f);
}

// ---------------- launch ----------------

extern "C" void kernel_launch(void* const* d_in, const int* in_sizes, int n_in,
                              void* d_out, int out_size, void* d_ws, size_t ws_size,
                              hipStream_t stream) {
    const float* doc0   = (const float*)d_in[0];
    const float* doc1   = (const float*)d_in[1];
    const float* doc2   = (const float*)d_in[2];
    const float* W1s    = (const float*)d_in[3];
    const float* b1s    = (const float*)d_in[4];
    const float* gammas = (const float*)d_in[5];
    const float* betas  = (const float*)d_in[6];
    const float* W2s    = (const float*)d_in[7];
    const float* b2s    = (const float*)d_in[8];
    float* out = (float*)d_out;

    char* base = (char*)d_ws;
    size_t off = 0;
    auto alloc = [&](size_t bytes) -> char* {
        char* r = base + off;
        off += (bytes + 255) & ~(size_t)255;
        return r;
    };

    unsigned short* Xb   = (unsigned short*)alloc((size_t)3 * N_ROWS * IN_DIM * 2);
    unsigned short* W1t  = (unsigned short*)alloc((size_t)6 * OUT_DIM * IN_DIM * 2);
    unsigned short* W2t  = (unsigned short*)alloc((size_t)6 * OUT_DIM * OUT_DIM * 2);
    unsigned short* Hb   = (unsigned short*)alloc((size_t)6 * N_ROWS * OUT_DIM * 2);
    unsigned short* O    = (unsigned short*)alloc((size_t)6 * N_ROWS * OUT_DIM * 2);
    unsigned short* Abuf = (unsigned short*)alloc((size_t)6 * N_ROWS * OUT_DIM * 2);
    float*          stats    = (float*)alloc((size_t)6 * OUT_DIM * 2 * 4);
    float*          rowsumsq = (float*)alloc((size_t)6 * N_ROWS * 4);
    float*          rowsum   = (float*)alloc((size_t)3 * 2 * N_ROWS * 4);
    float*          sdot     = (float*)alloc((size_t)3 * 2 * N_ROWS * 4);
    float*          cdot     = (float*)alloc((size_t)3 * 2 * N_ROWS * 4);

    if (ws_size < off) return;

    hipMemsetAsync(stats, 0, (size_t)6 * OUT_DIM * 2 * 4, stream);
    hipMemsetAsync(rowsumsq, 0, (size_t)6 * N_ROWS * 4, stream);
    hipMemsetAsync(rowsum, 0, (size_t)3 * 2 * N_ROWS * 4, stream);

    conv_docs<<<(3 * N_ROWS * IN_DIM / 4 + 255) / 256, 256, 0, stream>>>(doc0, doc1, doc2, Xb);
    transpose_conv<<<dim3(OUT_DIM / 32, IN_DIM / 32, 6), dim3(32, 8), 0, stream>>>(W1s, W1t, IN_DIM, OUT_DIM);
    transpose_conv<<<dim3(OUT_DIM / 32, OUT_DIM / 32, 6), dim3(32, 8), 0, stream>>>(W2s, W2t, OUT_DIM, OUT_DIM);

    gemm1_bn<<<dim3(OUT_DIM / BN, N_ROWS / BM, 6), 256, 0, stream>>>(Xb, W1t, b1s, Hb, stats);

    bn_apply<<<(int)(((size_t)6 * N_ROWS * OUT_DIM / 4 + 255) / 256), 256, 0, stream>>>(
        Hb, stats, gammas, betas);

    gemm2_norm<<<dim3(OUT_DIM / BN, N_ROWS / BM, 6), 256, 0, stream>>>(Hb, W2t, b2s, O, rowsumsq);

    l2norm<<<6 * N_ROWS / 4, 256, 0, stream>>>(O, rowsumsq, Abuf);

    // symmetric gram over 256-row supertiles: 32*33/2 = 528 blocks per pair
    gram_kernel<<<dim3(528, 1, 3), 512, 0, stream>>>(Abuf, rowsum, sdot, cdot);

    loss_kernel<<<1, 256, 0, stream>>>(rowsum, sdot, cdot, out);
}